// Round 6
// baseline (343.733 us; speedup 1.0000x reference)
//
#include <hip/hip_runtime.h>
#include <stdint.h>

// B=2, T=2048, DIM=1024, H=16, HD=64. Device tensors FLOAT32; internally
// convert to bf16 once, run bf16-MFMA pipeline, final GEMM writes f32.
//
// ws (40MB): xb@0 (8MB), wb@8MB (4x2MB), Kb@16MB [4096,1024],
// VT@24MB [32 bh][64 d][2048 t], Ob@32MB [4096,1024]. Qb (bf16, PRE-SCALED by
// 0.125*log2e) lives in d_out's first 8MB (dead before final GEMM).
//
// attn: swapped QK^T (mfma(K,Q) -> S^T) so each lane owns one q-row's scores
// => in-register softmax (2 shuffles/iter instead of 32), exp2 domain,
// diagonal-only causal mask, defer-max rescale (THR=8). PV computes O^T via
// mfma(V^T, P).

#define T_SEQ 2048
#define QSCALE 0.1803368801111204f   // 0.125 * log2(e)

typedef unsigned short u16;
typedef __attribute__((ext_vector_type(8))) __bf16 bf16x8;   // MFMA A/B frag
typedef __attribute__((ext_vector_type(4))) float  f32x4;    // MFMA C/D frag

#define NEG_BIG (-30000.0f)

__device__ __forceinline__ u16 f2bf(float x) {
    union { float f; unsigned u; } c; c.f = x;
    return (u16)((c.u + 0x7fffu + ((c.u >> 16) & 1u)) >> 16);
}

__device__ __forceinline__ void gload_lds16(const void* g, void* l) {
    __builtin_amdgcn_global_load_lds(
        (const __attribute__((address_space(1))) void*)g,
        (__attribute__((address_space(3))) void*)l, 16, 0, 0);
}

__device__ __forceinline__ void storeC(u16* p, float v)   { *p = f2bf(v); }
__device__ __forceinline__ void storeC(float* p, float v) { *p = v; }

// ---------------------------------------------------------------------------
// One launch converts x (1M float4) + 4 weights (256K float4 each) to bf16.
// ---------------------------------------------------------------------------
__global__ __launch_bounds__(256) void cvt_all(
    const float* __restrict__ x,  const float* __restrict__ wq,
    const float* __restrict__ wk, const float* __restrict__ wv,
    const float* __restrict__ wo, u16* __restrict__ xb, u16* __restrict__ wb)
{
    int i = blockIdx.x * 256 + threadIdx.x;        // 0 .. 2097151
    const float* s; u16* d; int off;
    if (i < 1048576) { s = x; d = xb; off = i; }
    else {
        int j = i - 1048576;
        int wsel = j >> 18;                        // 0..3
        off = j & 262143;
        s = wsel == 0 ? wq : wsel == 1 ? wk : wsel == 2 ? wv : wo;
        d = wb + (size_t)wsel * 1048576u;
    }
    float4 v = ((const float4*)s)[off];
    ushort4 o;
    o.x = f2bf(v.x); o.y = f2bf(v.y); o.z = f2bf(v.z); o.w = f2bf(v.w);
    ((ushort4*)d)[off] = o;
}

// ---------------------------------------------------------------------------
// GEMM: C[4096][1024] = A @ W^T (bf16, both K-contiguous). m97 structure.
// VT_MODE: z==2 writes C transposed per-head into VT[bh][d][t]; z==0 (Q)
// pre-scales the output by QSCALE.
// ---------------------------------------------------------------------------
template <typename OutT, bool VT_MODE>
__global__ __launch_bounds__(256) void gemm_bt(
    const u16* __restrict__ A, const u16* __restrict__ Wb,
    OutT* __restrict__ C0, OutT* __restrict__ C1, OutT* __restrict__ C2)
{
    __shared__ __align__(16) char As[128 * 128];
    __shared__ __align__(16) char Bs[128 * 128];

    const u16* W = Wb + (size_t)blockIdx.z * 1048576u;
    OutT* Cz = blockIdx.z == 0 ? C0 : (blockIdx.z == 1 ? C1 : C2);

    const int tid = threadIdx.x;
    const int w = tid >> 6, l = tid & 63;
    const int wy = w >> 1, wx = w & 1;
    const int bm = blockIdx.y * 128, bn = blockIdx.x * 128;

    f32x4 acc[4][4];
#pragma unroll
    for (int m = 0; m < 4; m++)
#pragma unroll
        for (int n = 0; n < 4; n++) acc[m][n] = (f32x4){0.f, 0.f, 0.f, 0.f};

    const int lrow = l >> 3, lslot = l & 7;

    for (int kt = 0; kt < 16; ++kt) {
#pragma unroll
        for (int c = 0; c < 4; ++c) {
            int ch = w * 4 + c;
            int row = ch * 8 + lrow;
            gload_lds16((const char*)A + ((size_t)(bm + row) * 1024 + kt * 64) * 2 + lslot * 16,
                        As + ch * 1024);
            gload_lds16((const char*)W + ((size_t)(bn + row) * 1024 + kt * 64) * 2 + lslot * 16,
                        Bs + ch * 1024);
        }
        __syncthreads();

#pragma unroll
        for (int kk = 0; kk < 2; ++kk) {
            const int cb = (kk * 32 + (l >> 4) * 8) * 2;
            bf16x8 af[4], bfr[4];
#pragma unroll
            for (int m = 0; m < 4; m++)
                af[m] = *(const bf16x8*)(As + (wy * 64 + m * 16 + (l & 15)) * 128 + cb);
#pragma unroll
            for (int n = 0; n < 4; n++)
                bfr[n] = *(const bf16x8*)(Bs + (wx * 64 + n * 16 + (l & 15)) * 128 + cb);
#pragma unroll
            for (int m = 0; m < 4; m++)
#pragma unroll
                for (int n = 0; n < 4; n++)
                    acc[m][n] = __builtin_amdgcn_mfma_f32_16x16x32_bf16(
                        af[m], bfr[n], acc[m][n], 0, 0, 0);
        }
        __syncthreads();
    }

    const bool vtw = VT_MODE && (blockIdx.z == 2);
    const float osc = (VT_MODE && blockIdx.z == 0) ? QSCALE : 1.0f;
#pragma unroll
    for (int m = 0; m < 4; m++) {
        int grow0 = bm + wy * 64 + m * 16 + (l >> 4) * 4;
#pragma unroll
        for (int n = 0; n < 4; n++) {
            int gcol = bn + wx * 64 + n * 16 + (l & 15);
            if (vtw) {
                int bh = (grow0 >> 11) * 16 + (gcol >> 6);
                size_t rowbase = ((size_t)bh * 64 + (gcol & 63)) * T_SEQ + (grow0 & 2047);
#pragma unroll
                for (int r = 0; r < 4; r++)
                    storeC(&Cz[rowbase + r], acc[m][n][r]);
            } else {
#pragma unroll
                for (int r = 0; r < 4; r++)
                    storeC(&Cz[(size_t)(grow0 + r) * 1024 + gcol], acc[m][n][r] * osc);
            }
        }
    }
}

// ---------------------------------------------------------------------------
// Flash attention, causal, 1 wave/block, QBLK=16, KVBLK=64.
// Swapped QK^T: s = mfma(K,Q) = S^T -> lane owns q-row (l&15), 16 scores in
// regs (k = nt*16 + (l>>4)*4 + r), replicated across 4 lane-groups.
// Softmax fully in-register (+2 shuffles). PV: oacc = mfma(V^T, P) = O^T.
// Q is pre-scaled by 0.125*log2e; exp2 domain throughout.
// ---------------------------------------------------------------------------
__global__ __launch_bounds__(64) void attn_fwd(
    const u16* __restrict__ Q, const u16* __restrict__ K,
    const u16* __restrict__ VT, u16* __restrict__ O)
{
    __shared__ __align__(16) u16 Ps[16][72];       // P[q][k] for this wave

    const int bh = blockIdx.x;                     // 0..31
    const int y = blockIdx.y;                      // 0..127
    const int qt = (y & 1) ? (127 - (y >> 1)) : (y >> 1);
    const int b = bh >> 4, h = bh & 15;
    const int l = threadIdx.x;
    const int g = l >> 4, q16 = l & 15;
    const size_t base = (size_t)b * T_SEQ * 1024 + h * 64;
    const u16* vtb = VT + (size_t)bh * 64 * T_SEQ;

    const int qg = qt * 16;
    const int qrow_g = qg + q16;                   // this lane's q row

    // Q as B-frag: n=q16, k=g*8+e (+32 per kk)
    const u16* qp = Q + base + (size_t)qrow_g * 1024 + g * 8;
    bf16x8 qf[2];
    qf[0] = *(const bf16x8*)(qp);
    qf[1] = *(const bf16x8*)(qp + 32);

    f32x4 oacc[4];                                 // O^T: d = nt*16+g*4+r, q = q16
#pragma unroll
    for (int n = 0; n < 4; n++) oacc[n] = (f32x4){0.f, 0.f, 0.f, 0.f};
    float mrun = NEG_BIG, lrun = 0.f;

    const int ktmax = (qg + 15) >> 6;

    for (int kt = 0; kt <= ktmax; ++kt) {
        const bool diag = (kt == ktmax);

        // ---- S^T = K Q^T : A-frag = K rows (k), B-frag = Q rows (q)
        f32x4 s[4];
#pragma unroll
        for (int n = 0; n < 4; n++) s[n] = (f32x4){0.f, 0.f, 0.f, 0.f};
#pragma unroll
        for (int kk = 0; kk < 2; ++kk) {
#pragma unroll
            for (int nt = 0; nt < 4; ++nt) {
                if (kt * 64 + nt * 16 <= qg + 15) {
                    bf16x8 kf = *(const bf16x8*)(K + base
                        + (size_t)(kt * 64 + nt * 16 + q16) * 1024
                        + kk * 32 + g * 8);
                    s[nt] = __builtin_amdgcn_mfma_f32_16x16x32_bf16(kf, qf[kk], s[nt], 0, 0, 0);
                }
            }
        }

        // ---- causal mask: only the diagonal tile needs it
        if (diag) {
#pragma unroll
            for (int nt = 0; nt < 4; ++nt)
#pragma unroll
                for (int r = 0; r < 4; ++r) {
                    int kg = kt * 64 + nt * 16 + g * 4 + r;
                    if (kg > qrow_g) s[nt][r] = NEG_BIG;
                }
        }

        // ---- in-register row max (16 vals) + 2 cross-lane reduces
        float pm = s[0][0];
#pragma unroll
        for (int nt = 0; nt < 4; ++nt)
#pragma unroll
            for (int r = 0; r < 4; ++r) pm = fmaxf(pm, s[nt][r]);
        pm = fmaxf(pm, __shfl_xor(pm, 16));
        pm = fmaxf(pm, __shfl_xor(pm, 32));

        // ---- defer-max: skip rescale while tile max stays within 2^8
        const bool noresc = __all(pm <= mrun + 8.0f);
        float mnew = noresc ? mrun : fmaxf(mrun, pm);

        float rs = 0.f;
#pragma unroll
        for (int nt = 0; nt < 4; ++nt)
#pragma unroll
            for (int r = 0; r < 4; ++r) {
                float p = __builtin_amdgcn_exp2f(s[nt][r] - mnew);
                s[nt][r] = p;
                rs += p;
            }
        rs += __shfl_xor(rs, 16);
        rs += __shfl_xor(rs, 32);

        if (!noresc) {
            float alpha = __builtin_amdgcn_exp2f(mrun - mnew);
            lrun *= alpha;
#pragma unroll
            for (int nt = 0; nt < 4; ++nt)
#pragma unroll
                for (int r = 0; r < 4; ++r) oacc[nt][r] *= alpha;
            mrun = mnew;
        }
        lrun += rs;

        // ---- P -> LDS: lane writes Ps[q16][nt*16+g*4 .. +3] (b64 packs)
#pragma unroll
        for (int nt = 0; nt < 4; ++nt) {
            ushort4 pk;
            pk.x = f2bf(s[nt][0]); pk.y = f2bf(s[nt][1]);
            pk.z = f2bf(s[nt][2]); pk.w = f2bf(s[nt][3]);
            *(ushort4*)(&Ps[q16][nt * 16 + g * 4]) = pk;
        }

        // ---- O^T += V^T P^T : A-frag = V^T rows (d), B-frag = Ps rows (q)
#pragma unroll
        for (int kk = 0; kk < 2; ++kk) {
            if (kt * 64 + kk * 32 <= qg + 15) {
                bf16x8 pf = *(const bf16x8*)(&Ps[q16][kk * 32 + g * 8]);
#pragma unroll
                for (int nt = 0; nt < 4; ++nt) {
                    bf16x8 vf = *(const bf16x8*)(vtb
                        + (size_t)(nt * 16 + q16) * T_SEQ
                        + kt * 64 + kk * 32 + g * 8);
                    oacc[nt] = __builtin_amdgcn_mfma_f32_16x16x32_bf16(vf, pf, oacc[nt], 0, 0, 0);
                }
            }
        }
    }

    // ---- epilogue: O[q][d] = oacc^T / lrun  (b64 stores, 4 cols per lane)
    const float rinv = __builtin_amdgcn_rcpf(lrun);
    u16* orow = O + (size_t)b * T_SEQ * 1024 + (size_t)(qg + q16) * 1024 + h * 64;
#pragma unroll
    for (int nt = 0; nt < 4; ++nt) {
        ushort4 ov;
        ov.x = f2bf(oacc[nt][0] * rinv); ov.y = f2bf(oacc[nt][1] * rinv);
        ov.z = f2bf(oacc[nt][2] * rinv); ov.w = f2bf(oacc[nt][3] * rinv);
        *(ushort4*)(orow + nt * 16 + g * 4) = ov;
    }
}

// ---------------------------------------------------------------------------
extern "C" void kernel_launch(void* const* d_in, const int* in_sizes, int n_in,
                              void* d_out, int out_size, void* d_ws, size_t ws_size,
                              hipStream_t stream)
{
    (void)in_sizes; (void)n_in; (void)out_size; (void)ws_size;
    const float* x  = (const float*)d_in[0];
    const float* wq = (const float*)d_in[1];
    const float* wk = (const float*)d_in[2];
    const float* wv = (const float*)d_in[3];
    const float* wo = (const float*)d_in[4];
    float* out = (float*)d_out;

    char* ws = (char*)d_ws;
    u16* xb = (u16*)(ws);                    // x bf16, 8MB
    u16* wb = (u16*)(ws + (8u << 20));       // wq,wk,wv,wo bf16
    u16* Kb = (u16*)(ws + (16u << 20));      // [4096,1024]
    u16* VT = (u16*)(ws + (24u << 20));      // [32][64][2048] V^T
    u16* Ob = (u16*)(ws + (32u << 20));      // [4096,1024]
    u16* Qb = (u16*)d_out;                   // Q bf16 (pre-scaled) in d_out

    dim3 blk(256);
    cvt_all<<<8192, blk, 0, stream>>>(x, wq, wk, wv, wo, xb, wb);

    // Q (scaled), K row-major; V written transposed into VT
    gemm_bt<u16, true><<<dim3(8, 32, 3), blk, 0, stream>>>(xb, wb, Qb, Kb, VT);
    // causal flash attention: 1-wave blocks, 16 q-rows each
    attn_fwd<<<dim3(32, 128, 1), dim3(64), 0, stream>>>(Qb, Kb, VT, Ob);
    // out = O @ wo^T (f32)
    gemm_bt<float, false><<<dim3(8, 32, 1), blk, 0, stream>>>(Ob, wb + 3u * 1048576u,
                                                              out, out, out);
}

// Round 7
// 257.897 us; speedup vs baseline: 1.3328x; 1.3328x over previous
//
#include <hip/hip_runtime.h>
#include <stdint.h>

// B=2, T=2048, DIM=1024, H=16, HD=64. Device tensors FLOAT32; internally
// convert to bf16 once, run bf16-MFMA pipeline, final GEMM writes f32.
//
// ws (40MB): xb@0 (8MB), wb@8MB (4x2MB), Kb@16MB [4096,1024],
// VT@24MB [32 bh][64 d][2048 t], Ob@32MB [4096,1024]. Qb (bf16, PRE-SCALED by
// 0.125*log2e) lives in d_out's first 8MB (dead before final GEMM).
//
// attn: swapped QK^T (mfma(K,Q)=S^T, lane owns one q-row). TWO independent
// q-tile chains per wave (tiles 2y, 2y+1 share the same kt range -> shared
// K/V fragment loads), tree reductions, peeled diagonal iteration, exp2
// domain, defer-max. PV computes O^T via mfma(V^T, P).

#define T_SEQ 2048
#define QSCALE 0.1803368801111204f   // 0.125 * log2(e)

typedef unsigned short u16;
typedef __attribute__((ext_vector_type(8))) __bf16 bf16x8;   // MFMA A/B frag
typedef __attribute__((ext_vector_type(4))) float  f32x4;    // MFMA C/D frag

#define NEG_BIG (-30000.0f)

__device__ __forceinline__ u16 f2bf(float x) {
    union { float f; unsigned u; } c; c.f = x;
    return (u16)((c.u + 0x7fffu + ((c.u >> 16) & 1u)) >> 16);
}

__device__ __forceinline__ void gload_lds16(const void* g, void* l) {
    __builtin_amdgcn_global_load_lds(
        (const __attribute__((address_space(1))) void*)g,
        (__attribute__((address_space(3))) void*)l, 16, 0, 0);
}

__device__ __forceinline__ void storeC(u16* p, float v)   { *p = f2bf(v); }
__device__ __forceinline__ void storeC(float* p, float v) { *p = v; }

// ---------------------------------------------------------------------------
__global__ __launch_bounds__(256) void cvt_all(
    const float* __restrict__ x,  const float* __restrict__ wq,
    const float* __restrict__ wk, const float* __restrict__ wv,
    const float* __restrict__ wo, u16* __restrict__ xb, u16* __restrict__ wb)
{
    int i = blockIdx.x * 256 + threadIdx.x;        // 0 .. 2097151
    const float* s; u16* d; int off;
    if (i < 1048576) { s = x; d = xb; off = i; }
    else {
        int j = i - 1048576;
        int wsel = j >> 18;
        off = j & 262143;
        s = wsel == 0 ? wq : wsel == 1 ? wk : wsel == 2 ? wv : wo;
        d = wb + (size_t)wsel * 1048576u;
    }
    float4 v = ((const float4*)s)[off];
    ushort4 o;
    o.x = f2bf(v.x); o.y = f2bf(v.y); o.z = f2bf(v.z); o.w = f2bf(v.w);
    ((ushort4*)d)[off] = o;
}

// ---------------------------------------------------------------------------
// GEMM: C[4096][1024] = A @ W^T (bf16, both K-contiguous). m97 structure.
// VT_MODE: z==2 writes C transposed per-head into VT[bh][d][t]; z==0 (Q)
// pre-scales output by QSCALE.
// ---------------------------------------------------------------------------
template <typename OutT, bool VT_MODE>
__global__ __launch_bounds__(256) void gemm_bt(
    const u16* __restrict__ A, const u16* __restrict__ Wb,
    OutT* __restrict__ C0, OutT* __restrict__ C1, OutT* __restrict__ C2)
{
    __shared__ __align__(16) char As[128 * 128];
    __shared__ __align__(16) char Bs[128 * 128];

    const u16* W = Wb + (size_t)blockIdx.z * 1048576u;
    OutT* Cz = blockIdx.z == 0 ? C0 : (blockIdx.z == 1 ? C1 : C2);

    const int tid = threadIdx.x;
    const int w = tid >> 6, l = tid & 63;
    const int wy = w >> 1, wx = w & 1;
    const int bm = blockIdx.y * 128, bn = blockIdx.x * 128;

    f32x4 acc[4][4];
#pragma unroll
    for (int m = 0; m < 4; m++)
#pragma unroll
        for (int n = 0; n < 4; n++) acc[m][n] = (f32x4){0.f, 0.f, 0.f, 0.f};

    const int lrow = l >> 3, lslot = l & 7;

    for (int kt = 0; kt < 16; ++kt) {
#pragma unroll
        for (int c = 0; c < 4; ++c) {
            int ch = w * 4 + c;
            int row = ch * 8 + lrow;
            gload_lds16((const char*)A + ((size_t)(bm + row) * 1024 + kt * 64) * 2 + lslot * 16,
                        As + ch * 1024);
            gload_lds16((const char*)W + ((size_t)(bn + row) * 1024 + kt * 64) * 2 + lslot * 16,
                        Bs + ch * 1024);
        }
        __syncthreads();

#pragma unroll
        for (int kk = 0; kk < 2; ++kk) {
            const int cb = (kk * 32 + (l >> 4) * 8) * 2;
            bf16x8 af[4], bfr[4];
#pragma unroll
            for (int m = 0; m < 4; m++)
                af[m] = *(const bf16x8*)(As + (wy * 64 + m * 16 + (l & 15)) * 128 + cb);
#pragma unroll
            for (int n = 0; n < 4; n++)
                bfr[n] = *(const bf16x8*)(Bs + (wx * 64 + n * 16 + (l & 15)) * 128 + cb);
#pragma unroll
            for (int m = 0; m < 4; m++)
#pragma unroll
                for (int n = 0; n < 4; n++)
                    acc[m][n] = __builtin_amdgcn_mfma_f32_16x16x32_bf16(
                        af[m], bfr[n], acc[m][n], 0, 0, 0);
        }
        __syncthreads();
    }

    const bool vtw = VT_MODE && (blockIdx.z == 2);
    const float osc = (VT_MODE && blockIdx.z == 0) ? QSCALE : 1.0f;
#pragma unroll
    for (int m = 0; m < 4; m++) {
        int grow0 = bm + wy * 64 + m * 16 + (l >> 4) * 4;
#pragma unroll
        for (int n = 0; n < 4; n++) {
            int gcol = bn + wx * 64 + n * 16 + (l & 15);
            if (vtw) {
                int bh = (grow0 >> 11) * 16 + (gcol >> 6);
                size_t rowbase = ((size_t)bh * 64 + (gcol & 63)) * T_SEQ + (grow0 & 2047);
#pragma unroll
                for (int r = 0; r < 4; r++)
                    storeC(&Cz[rowbase + r], acc[m][n][r]);
            } else {
#pragma unroll
                for (int r = 0; r < 4; r++)
                    storeC(&Cz[(size_t)(grow0 + r) * 1024 + gcol], acc[m][n][r] * osc);
            }
        }
    }
}

// ---------------------------------------------------------------------------
// softmax step for one chain (tree reductions, defer-max). Lane owns q-row
// qrow_g; its 16 scores are s[nt][r] at k = kbase + nt*16 + g*4 + r.
// ---------------------------------------------------------------------------
__device__ __forceinline__ void online_sm(
    f32x4 (&s)[4], f32x4 (&oacc)[4], float& mrun, float& lrun,
    int qrow_g, int kbase, bool diag, int g, u16 (*__restrict__ Ps)[72], int q16)
{
    if (diag) {
#pragma unroll
        for (int nt = 0; nt < 4; ++nt)
#pragma unroll
            for (int r = 0; r < 4; ++r)
                if (kbase + nt * 16 + g * 4 + r > qrow_g) s[nt][r] = NEG_BIG;
    }
    // tree max (depth 4) + 2 cross-group reduces
    float a0 = fmaxf(fmaxf(s[0][0], s[0][1]), fmaxf(s[0][2], s[0][3]));
    float a1 = fmaxf(fmaxf(s[1][0], s[1][1]), fmaxf(s[1][2], s[1][3]));
    float a2 = fmaxf(fmaxf(s[2][0], s[2][1]), fmaxf(s[2][2], s[2][3]));
    float a3 = fmaxf(fmaxf(s[3][0], s[3][1]), fmaxf(s[3][2], s[3][3]));
    float pm = fmaxf(fmaxf(a0, a1), fmaxf(a2, a3));
    pm = fmaxf(pm, __shfl_xor(pm, 16));
    pm = fmaxf(pm, __shfl_xor(pm, 32));

    const bool noresc = __all(pm <= mrun + 8.0f);
    const float mnew = noresc ? mrun : fmaxf(mrun, pm);

#pragma unroll
    for (int nt = 0; nt < 4; ++nt)
#pragma unroll
        for (int r = 0; r < 4; ++r)
            s[nt][r] = __builtin_amdgcn_exp2f(s[nt][r] - mnew);

    // tree sum (depth 4) + 2 cross-group reduces
    float b0 = (s[0][0] + s[0][1]) + (s[0][2] + s[0][3]);
    float b1 = (s[1][0] + s[1][1]) + (s[1][2] + s[1][3]);
    float b2 = (s[2][0] + s[2][1]) + (s[2][2] + s[2][3]);
    float b3 = (s[3][0] + s[3][1]) + (s[3][2] + s[3][3]);
    float rs = (b0 + b1) + (b2 + b3);
    rs += __shfl_xor(rs, 16);
    rs += __shfl_xor(rs, 32);

    if (!noresc) {
        float alpha = __builtin_amdgcn_exp2f(mrun - mnew);
        lrun *= alpha;
#pragma unroll
        for (int nt = 0; nt < 4; ++nt)
#pragma unroll
            for (int r = 0; r < 4; ++r) oacc[nt][r] *= alpha;
        mrun = mnew;
    }
    lrun += rs;

    // pack P -> LDS (b64 per nt)
#pragma unroll
    for (int nt = 0; nt < 4; ++nt) {
        ushort4 pk;
        pk.x = f2bf(s[nt][0]); pk.y = f2bf(s[nt][1]);
        pk.z = f2bf(s[nt][2]); pk.w = f2bf(s[nt][3]);
        *(ushort4*)(&Ps[q16][nt * 16 + g * 4]) = pk;
    }
}

// ---------------------------------------------------------------------------
// Flash attention, causal, 1 wave/block, TWO 16-row q-tiles per wave
// (q-tiles 2y and 2y+1 — identical kt range, shared K/V loads).
// ---------------------------------------------------------------------------
__global__ __launch_bounds__(64) void attn_fwd(
    const u16* __restrict__ Q, const u16* __restrict__ K,
    const u16* __restrict__ VT, u16* __restrict__ O)
{
    __shared__ __align__(16) u16 PsA[16][72];
    __shared__ __align__(16) u16 PsB[16][72];

    const int bh = blockIdx.x;                     // 0..31
    const int y0 = blockIdx.y;                     // 0..63
    const int y = (y0 & 1) ? (63 - (y0 >> 1)) : (y0 >> 1);   // balance
    const int b = bh >> 4, h = bh & 15;
    const int l = threadIdx.x;
    const int g = l >> 4, q16 = l & 15;
    const size_t base = (size_t)b * T_SEQ * 1024 + h * 64;
    const u16* vtb = VT + (size_t)bh * 64 * T_SEQ;

    const int qgA = y * 32, qgB = qgA + 16;
    const int qrA = qgA + q16, qrB = qgB + q16;    // lanes' q rows
    const int ktmax = (qgA + 31) >> 6;             // same for both tiles

    const u16* qpA = Q + base + (size_t)qrA * 1024 + g * 8;
    const u16* qpB = Q + base + (size_t)qrB * 1024 + g * 8;
    bf16x8 qfA[2], qfB[2];
    qfA[0] = *(const bf16x8*)(qpA); qfA[1] = *(const bf16x8*)(qpA + 32);
    qfB[0] = *(const bf16x8*)(qpB); qfB[1] = *(const bf16x8*)(qpB + 32);

    f32x4 oaccA[4], oaccB[4];
#pragma unroll
    for (int n = 0; n < 4; n++) {
        oaccA[n] = (f32x4){0.f, 0.f, 0.f, 0.f};
        oaccB[n] = (f32x4){0.f, 0.f, 0.f, 0.f};
    }
    float mA = NEG_BIG, lA = 0.f, mB = NEG_BIG, lB = 0.f;

    auto run_iter = [&](int kt, bool diag) {
        const int kbase = kt * 64;

        // ---- shared K / V^T fragment loads (issued first, hidden by compute)
        bf16x8 kf[2][4], vf[2][4];
#pragma unroll
        for (int kk = 0; kk < 2; ++kk)
#pragma unroll
            for (int nt = 0; nt < 4; ++nt) {
                kf[kk][nt] = *(const bf16x8*)(K + base
                    + (size_t)(kbase + nt * 16 + q16) * 1024 + kk * 32 + g * 8);
                vf[kk][nt] = *(const bf16x8*)(vtb
                    + (size_t)(nt * 16 + q16) * T_SEQ + kbase + kk * 32 + g * 8);
            }

        // ---- S^T for both chains (independent MFMA streams)
        f32x4 sA[4], sB[4];
#pragma unroll
        for (int n = 0; n < 4; n++) {
            sA[n] = (f32x4){0.f, 0.f, 0.f, 0.f};
            sB[n] = (f32x4){0.f, 0.f, 0.f, 0.f};
        }
#pragma unroll
        for (int kk = 0; kk < 2; ++kk)
#pragma unroll
            for (int nt = 0; nt < 4; ++nt) {
                if (!diag || (kbase + nt * 16 <= qgA + 15))
                    sA[nt] = __builtin_amdgcn_mfma_f32_16x16x32_bf16(
                        kf[kk][nt], qfA[kk], sA[nt], 0, 0, 0);
                if (!diag || (kbase + nt * 16 <= qgB + 15))
                    sB[nt] = __builtin_amdgcn_mfma_f32_16x16x32_bf16(
                        kf[kk][nt], qfB[kk], sB[nt], 0, 0, 0);
            }

        // ---- two independent softmaxes (ILP)
        online_sm(sA, oaccA, mA, lA, qrA, kbase, diag, g, PsA, q16);
        online_sm(sB, oaccB, mB, lB, qrB, kbase, diag, g, PsB, q16);

        // ---- O^T += V^T P^T for both chains
#pragma unroll
        for (int kk = 0; kk < 2; ++kk) {
            bf16x8 pfA = *(const bf16x8*)(&PsA[q16][kk * 32 + g * 8]);
            bf16x8 pfB = *(const bf16x8*)(&PsB[q16][kk * 32 + g * 8]);
            const bool okA = !diag || (kbase + kk * 32 <= qgA + 15);
            const bool okB = !diag || (kbase + kk * 32 <= qgB + 15);
#pragma unroll
            for (int nt = 0; nt < 4; ++nt) {
                if (okA)
                    oaccA[nt] = __builtin_amdgcn_mfma_f32_16x16x32_bf16(
                        vf[kk][nt], pfA, oaccA[nt], 0, 0, 0);
                if (okB)
                    oaccB[nt] = __builtin_amdgcn_mfma_f32_16x16x32_bf16(
                        vf[kk][nt], pfB, oaccB[nt], 0, 0, 0);
            }
        }
    };

    for (int kt = 0; kt < ktmax; ++kt) run_iter(kt, false);   // mask-free body
    run_iter(ktmax, true);                                    // peeled diagonal

    // ---- epilogue: O[q][d] = oacc^T / lrun for both tiles
    const float riA = __builtin_amdgcn_rcpf(lA);
    const float riB = __builtin_amdgcn_rcpf(lB);
    u16* orowA = O + (size_t)b * T_SEQ * 1024 + (size_t)qrA * 1024 + h * 64;
    u16* orowB = O + (size_t)b * T_SEQ * 1024 + (size_t)qrB * 1024 + h * 64;
#pragma unroll
    for (int nt = 0; nt < 4; ++nt) {
        ushort4 oa, ob;
        oa.x = f2bf(oaccA[nt][0] * riA); oa.y = f2bf(oaccA[nt][1] * riA);
        oa.z = f2bf(oaccA[nt][2] * riA); oa.w = f2bf(oaccA[nt][3] * riA);
        ob.x = f2bf(oaccB[nt][0] * riB); ob.y = f2bf(oaccB[nt][1] * riB);
        ob.z = f2bf(oaccB[nt][2] * riB); ob.w = f2bf(oaccB[nt][3] * riB);
        *(ushort4*)(orowA + nt * 16 + g * 4) = oa;
        *(ushort4*)(orowB + nt * 16 + g * 4) = ob;
    }
}

// ---------------------------------------------------------------------------
extern "C" void kernel_launch(void* const* d_in, const int* in_sizes, int n_in,
                              void* d_out, int out_size, void* d_ws, size_t ws_size,
                              hipStream_t stream)
{
    (void)in_sizes; (void)n_in; (void)out_size; (void)ws_size;
    const float* x  = (const float*)d_in[0];
    const float* wq = (const float*)d_in[1];
    const float* wk = (const float*)d_in[2];
    const float* wv = (const float*)d_in[3];
    const float* wo = (const float*)d_in[4];
    float* out = (float*)d_out;

    char* ws = (char*)d_ws;
    u16* xb = (u16*)(ws);                    // x bf16, 8MB
    u16* wb = (u16*)(ws + (8u << 20));       // wq,wk,wv,wo bf16
    u16* Kb = (u16*)(ws + (16u << 20));      // [4096,1024]
    u16* VT = (u16*)(ws + (24u << 20));      // [32][64][2048] V^T
    u16* Ob = (u16*)(ws + (32u << 20));      // [4096,1024]
    u16* Qb = (u16*)d_out;                   // Q bf16 (pre-scaled) in d_out

    dim3 blk(256);
    cvt_all<<<8192, blk, 0, stream>>>(x, wq, wk, wv, wo, xb, wb);

    // Q (scaled), K row-major; V written transposed into VT
    gemm_bt<u16, true><<<dim3(8, 32, 3), blk, 0, stream>>>(xb, wb, Qb, Kb, VT);
    // causal flash attention: 1-wave blocks, two 16-row q-tiles each
    attn_fwd<<<dim3(32, 64, 1), dim3(64), 0, stream>>>(Qb, Kb, VT, Ob);
    // out = O @ wo^T (f32)
    gemm_bt<float, false><<<dim3(8, 32, 1), blk, 0, stream>>>(Ob, wb + 3u * 1048576u,
                                                              out, out, out);
}